// Round 9
// baseline (218.351 us; speedup 1.0000x reference)
//
#include <hip/hip_runtime.h>

// WL graph kernel: G=64 graphs, N=4096 nodes, D=16 neighbors, 4 iterations.
// K = cosine-normalized Gram of summed per-iteration label histograms.
//
// R9: K = W*W^T (iter 0) + 4*diag(s_g) (singleton classes) + rare multi-member
// corrections. Dedup via ONE 64-bit CAS per node: table[pos]=(tag32<<32)|(idx+1)
// claims the class slot and publishes the representative. Labels ARE the slots.
// NEW: per-iteration DISJOINT 2^19-slot table regions (4 MB working set, was a
// shared 16 MB): 262k random CAS land on 64k lines (~4/line) instead of 262k,
// cutting the random-line HBM traffic that pinned k_hash at ~45us. Still only
// ONE up-front memset (regions are disjoint -> no per-iteration clears).

#define GG 64
#define NN 4096
#define DD 16
#define TT 4

static constexpr int GN = GG * NN;             // 262144 nodes
static constexpr int RBITS = 19;               // 2^19 slots per iteration region
static constexpr unsigned RMASK = (1u << RBITS) - 1;
static constexpr size_t TBYTES = (size_t)TT * ((size_t)8 << RBITS);  // 16 MB total
static constexpr int OVF_MAX = GN;

__device__ __forceinline__ unsigned long long mix64(unsigned long long x) {
    x += 0x9E3779B97F4A7C15ull;
    x = (x ^ (x >> 30)) * 0xBF58476D1CE4E5B9ull;
    x = (x ^ (x >> 27)) * 0x94D049BB133111EBull;
    return x ^ (x >> 31);
}

// labels[g][i] = i;  wT[i][g] = w[g][i]  (for the iteration-0 W*W^T fold)
__global__ void k_init(int* __restrict__ labels, const float* __restrict__ w,
                       float* __restrict__ wT) {
    int idx = blockIdx.x * blockDim.x + threadIdx.x;   // 0..GN
    labels[idx] = idx & (NN - 1);
    int i = idx >> 6, g = idx & 63;
    wT[idx] = w[(g << 12) | i];
}

// Signature hash + single-CAS dedup + label write. No LDS; L1/L2-hit gathers.
__global__ __launch_bounds__(256) void
k_hash(const int* __restrict__ labels, const int* __restrict__ nbr,
       unsigned long long* __restrict__ table, const float* __restrict__ w,
       double* __restrict__ K, unsigned long long* __restrict__ ovf,
       int* __restrict__ novf, int* __restrict__ labels_next,
       int base, int region, unsigned long long salt) {
    int idx = blockIdx.x * blockDim.x + threadIdx.x;   // 0..GN
    int g = idx >> 12;
    const int* lab = labels + (g << 12);
    int own = lab[idx & (NN - 1)];

    const int4* nb4 = reinterpret_cast<const int4*>(nbr + (size_t)idx * DD);
    int4 v0 = nb4[0], v1 = nb4[1], v2 = nb4[2], v3 = nb4[3];
    int l[16];
    l[0]=lab[v0.x]; l[1]=lab[v0.y]; l[2]=lab[v0.z]; l[3]=lab[v0.w];
    l[4]=lab[v1.x]; l[5]=lab[v1.y]; l[6]=lab[v1.z]; l[7]=lab[v1.w];
    l[8]=lab[v2.x]; l[9]=lab[v2.y]; l[10]=lab[v2.z]; l[11]=lab[v2.w];
    l[12]=lab[v3.x]; l[13]=lab[v3.y]; l[14]=lab[v3.z]; l[15]=lab[v3.w];

    unsigned long long acc = 0;
    bool keep = true;
#pragma unroll
    for (int q = 0; q < 16; ++q) {
        keep = keep & (l[q] == own);
        acc += mix64((unsigned long long)(unsigned)l[q]);
    }
    unsigned long long h =
        mix64(acc ^ mix64(((unsigned long long)(unsigned)own) + salt));

    unsigned p19 = (unsigned)h & RMASK;              // bits 0..18
    unsigned tag = (unsigned)(h >> 32);              // bits 32..63 (independent)
    unsigned long long val = ((unsigned long long)tag << 32) | (unsigned)(idx + 1);
    unsigned long long* reg = table + ((size_t)region << RBITS);
    int rep = -1;
    while (true) {
        unsigned long long old = atomicCAS(&reg[p19], 0ull, val);
        if (old == 0ull) break;                              // claimed: we are rep
        if ((unsigned)(old >> 32) == tag) {                  // same class
            rep = (int)(old & 0xFFFFFFFFull) - 1;
            break;
        }
        p19 = (p19 + 1) & RMASK;                             // occupied foreign slot
    }
    labels_next[idx] = keep ? own : (base + (int)p19);

    bool join = rep >= 0;                    // ~never on this input; exact path
    if (join) {
        double duv = (double)w[idx] * (double)w[rep];
        int gr = rep >> 12;
        atomicAdd(&K[(g << 6) | gr], duv);   // ordered pair (u, rep)
        atomicAdd(&K[(gr << 6) | g], duv);   // ordered pair (rep, u)
    }
    unsigned long long b = __ballot(join);
    if (b) {
        int lane = threadIdx.x & 63;
        int leader = (int)__ffsll(b) - 1;
        int bp = 0;
        if (lane == leader) bp = atomicAdd(novf, (int)__popcll(b));
        bp = __shfl(bp, leader, 64);
        if (join) {
            int p = bp + (int)__popcll(b & ((1ull << lane) - 1ull));
            if (p < OVF_MAX)
                ovf[p] = ((unsigned long long)p19 << 32) | (unsigned)idx;
        }
    }
}

// Joiner-joiner ordered pairs (same slot => same class). Usually novf == 0.
__global__ void k_resolve(const unsigned long long* __restrict__ ovf,
                          const int* __restrict__ novf,
                          const float* __restrict__ w, double* __restrict__ K) {
    int n = *novf;
    if (n > OVF_MAX) n = OVF_MAX;
    for (int i = blockIdx.x * blockDim.x + threadIdx.x; i < n;
         i += gridDim.x * blockDim.x) {
        unsigned long long e = ovf[i];
        unsigned pos = (unsigned)(e >> 32);
        int u = (int)(e & 0xFFFFFFFFull);
        int gu = u >> 12;
        double wu = w[u];
        for (int j = 0; j < n; ++j) {
            if (j == i) continue;
            unsigned long long f = ovf[j];
            if ((unsigned)(f >> 32) != pos) continue;
            int v = (int)(f & 0xFFFFFFFFull);
            atomicAdd(&K[(gu << 6) | (v >> 12)], wu * (double)w[v]);
        }
    }
}

// s_g = sum_u w[g][u]^2  (one block per graph)
__global__ void k_diag(const float* __restrict__ w, double* __restrict__ sdiag) {
    int g = blockIdx.x;
    const float4* w4 = reinterpret_cast<const float4*>(w + (g << 12));
    double s = 0.0;
    for (int k = threadIdx.x; k < NN / 4; k += 256) {
        float4 v = w4[k];
        s += (double)v.x * v.x + (double)v.y * v.y
           + (double)v.z * v.z + (double)v.w * v.w;
    }
#pragma unroll
    for (int o = 32; o > 0; o >>= 1) s += __shfl_down(s, o, 64);
    __shared__ double part[4];
    if ((threadIdx.x & 63) == 0) part[threadIdx.x >> 6] = s;
    __syncthreads();
    if (threadIdx.x == 0) sdiag[g] = part[0] + part[1] + part[2] + part[3];
}

// Fold K += src^T * src over [rows][64]; thread owns 4x4 tile of 64x64 K.
__global__ void k_fold(const float* __restrict__ src, double* __restrict__ K,
                       int chunk) {
    int e0 = blockIdx.x * chunk;
    __shared__ float v[32 * 64];
    float acc[16];
#pragma unroll
    for (int k = 0; k < 16; ++k) acc[k] = 0.f;
    int r0 = (threadIdx.x >> 4) << 2;
    int c0 = (threadIdx.x & 15) << 2;

    for (int s0 = 0; s0 < chunk; s0 += 32) {
        const float4* s4 = reinterpret_cast<const float4*>(src + (size_t)(e0 + s0) * 64);
        float4* dv = reinterpret_cast<float4*>(v);
        dv[threadIdx.x] = s4[threadIdx.x];
        dv[threadIdx.x + 256] = s4[threadIdx.x + 256];
        __syncthreads();
#pragma unroll
        for (int e = 0; e < 32; ++e) {
            const float4 a = *reinterpret_cast<const float4*>(&v[e * 64 + r0]);
            const float4 b = *reinterpret_cast<const float4*>(&v[e * 64 + c0]);
            acc[0]  += a.x * b.x; acc[1]  += a.x * b.y; acc[2]  += a.x * b.z; acc[3]  += a.x * b.w;
            acc[4]  += a.y * b.x; acc[5]  += a.y * b.y; acc[6]  += a.y * b.z; acc[7]  += a.y * b.w;
            acc[8]  += a.z * b.x; acc[9]  += a.z * b.y; acc[10] += a.z * b.z; acc[11] += a.z * b.w;
            acc[12] += a.w * b.x; acc[13] += a.w * b.y; acc[14] += a.w * b.z; acc[15] += a.w * b.w;
        }
        __syncthreads();
    }
#pragma unroll
    for (int i = 0; i < 4; ++i)
#pragma unroll
        for (int j = 0; j < 4; ++j)
            atomicAdd(&K[(r0 + i) * 64 + (c0 + j)], (double)acc[i * 4 + j]);
}

__global__ void k_norm(const double* __restrict__ K, const double* __restrict__ sdiag,
                       float* __restrict__ out) {
    int idx = blockIdx.x * blockDim.x + threadIdx.x;   // 4096
    int r = idx >> 6, c = idx & 63;
    double kd = K[idx] + (r == c ? 4.0 * sdiag[r] : 0.0);
    double dr = K[(r << 6) | r] + 4.0 * sdiag[r];
    double dc = K[(c << 6) | c] + 4.0 * sdiag[c];
    out[idx] = (float)(kd / sqrt(dr * dc));
}

extern "C" void kernel_launch(void* const* d_in, const int* in_sizes, int n_in,
                              void* d_out, int out_size, void* d_ws, size_t ws_size,
                              hipStream_t stream) {
    const int* nbr = (const int*)d_in[0];       // [G, N, D] int32
    const float* w = (const float*)d_in[1];     // [G, N] float32
    float* out = (float*)d_out;                 // [G, G] float32

    char* ws = (char*)d_ws;
    size_t off = 0;
    auto alloc = [&](size_t bytes) -> void* {
        void* p = ws + off;
        off += (bytes + 255) & ~(size_t)255;
        return p;
    };
    double* Kacc  = (double*)alloc(64 * 64 * 8);                    // 32 KB
    int* counters = (int*)alloc(256);                               // novf[t]
    double* sdiag = (double*)alloc(64 * 8);                         // 512 B
    unsigned long long* table = (unsigned long long*)alloc(TBYTES); // 16 MB (4 regions)
    int* labelsA  = (int*)alloc((size_t)GN * 4);                    // 1 MB
    int* labelsB  = (int*)alloc((size_t)GN * 4);                    // 1 MB
    float* wT     = (float*)alloc((size_t)GN * 4);                  // 1 MB
    unsigned long long* ovf = (unsigned long long*)alloc((size_t)OVF_MAX * 8); // 2 MB

    // Kacc, counters, sdiag, table contiguous -> ONE zero-memset per call
    hipMemsetAsync(Kacc, 0, 64 * 64 * 8 + 256 + 512 + TBYTES, stream);

    const int BLK = 256;

    // iteration 0: labels = arange shared across graphs -> K0 = W W^T
    k_init<<<GN / BLK, BLK, 0, stream>>>(labelsA, w, wT);
    k_fold<<<32, BLK, 0, stream>>>(wT, Kacc, NN / 32);
    k_diag<<<GG, BLK, 0, stream>>>(w, sdiag);

    int* cur = labelsA;
    int* nxt = labelsB;
    for (int t = 0; t < TT; ++t) {
        unsigned long long salt = 0x0ABCDEF123456789ull + ((unsigned long long)(t + 1) << 33);
        k_hash<<<GN / BLK, BLK, 0, stream>>>(cur, nbr, table, w, Kacc, ovf,
                                             &counters[t], nxt,
                                             NN + t * (1 << RBITS), t, salt);
        k_resolve<<<64, BLK, 0, stream>>>(ovf, &counters[t], w, Kacc);
        int* tmp = cur; cur = nxt; nxt = tmp;
    }

    k_norm<<<(GG * GG) / BLK, BLK, 0, stream>>>(Kacc, sdiag, out);
}

// Round 16
// 107.811 us; speedup vs baseline: 2.0253x; 2.0253x over previous
//
#include <hip/hip_runtime.h>

// WL graph kernel: G=64 graphs, N=4096 nodes, D=16 neighbors, 4 iterations.
// K = cosine-normalized Gram of summed per-iteration label histograms.
//
// R10 structural theorem: signature at t contains own label, label_0 = node
// index u => every class at t>=1 is {(g,u): g in S} for a FIXED u. So:
//  t=1: dedup per-u among 64 graphs = wave-local shuffle scan of per-(g,u)
//       neighbor-index-multiset hashes. NO global atomics (the ~45us/pass
//       CAS cost that pinned R5-R9).
//  t>=2: partitions only refine within t=1 classes (monotone) -> only active
//       (u,g) pairs (members of multi-member t=1 classes; expected ZERO here)
//       are refined, via per-u class ids cls[u][g] and neighbor-class multiset
//       hashes. Fixed-launch kernels grid-stride over a device-side count.
// K = W*W^T (t=0) + 4*diag(s_g) (within-graph labels always distinct) +
//     scan pairs (t=1) + refine pairs (t=2..4).

#define GG 64
#define NN 4096
#define DD 16

static constexpr int GN = GG * NN;             // 262144
static constexpr int RBITS = 19;               // refine CAS region (worst case)
static constexpr unsigned RMASK = (1u << RBITS) - 1;
static constexpr size_t RTBYTES = (size_t)8 << RBITS;   // 4 MB per refine
static constexpr int OVFR = GN;                // per-refine ovf capacity

__device__ __forceinline__ unsigned long long mix64(unsigned long long x) {
    x += 0x9E3779B97F4A7C15ull;
    x = (x ^ (x >> 30)) * 0xBF58476D1CE4E5B9ull;
    x = (x ^ (x >> 27)) * 0x94D049BB133111EBull;
    return x ^ (x >> 31);
}

// wT[i][g] = w[g][i]; clsB identity (t=2 refine output default: singletons)
__global__ void k_init(const float* __restrict__ w, float* __restrict__ wT,
                       unsigned char* __restrict__ clsB) {
    int idx = blockIdx.x * blockDim.x + threadIdx.x;   // 0..GN (= NN*64)
    wT[idx] = w[((idx & 63) << 12) | (idx >> 6)];
    clsB[idx] = (unsigned char)(idx & 63);
}

// Per-(g,u) hash of the neighbor-index multiset (labels_0 = identity).
// idx = u*64+g: H writes coalesced; nbr reads 64B/thread, L1-reused.
__global__ __launch_bounds__(256) void
k_sig(const int* __restrict__ nbr, unsigned long long* __restrict__ H) {
    int idx = blockIdx.x * blockDim.x + threadIdx.x;   // u*64+g
    int u = idx >> 6, g = idx & 63;
    const int4* nb4 = reinterpret_cast<const int4*>(nbr + ((size_t)((g << 12) | u)) * DD);
    unsigned long long acc = 0;
#pragma unroll
    for (int q = 0; q < 4; ++q) {
        int4 v = nb4[q];
        acc += mix64((unsigned long long)(unsigned)v.x)
             + mix64((unsigned long long)(unsigned)v.y)
             + mix64((unsigned long long)(unsigned)v.z)
             + mix64((unsigned long long)(unsigned)v.w);
    }
    H[idx] = mix64(acc ^ mix64((unsigned long long)(unsigned)u + 0x0ABCDEF123456789ull));
}

// Wave = one u (64 lanes = 64 graphs). Shuffle-scan for equal hashes:
// inline ordered-pair adds (expected 0 matches), cls1[u][g] = min equal g,
// wave-aggregated push of active (u,g) pairs.
__global__ __launch_bounds__(256) void
k_scan(const unsigned long long* __restrict__ H, const float* __restrict__ w,
       double* __restrict__ K, unsigned char* __restrict__ cls1,
       int* __restrict__ act, int* __restrict__ nact) {
    int idx = blockIdx.x * blockDim.x + threadIdx.x;   // u*64+g
    int u = idx >> 6, g = idx & 63;
    unsigned long long h = H[idx];
    float wu = w[(g << 12) | u];
    int rep = g;
    bool active = false;
#pragma unroll 4
    for (int j = 0; j < 64; ++j) {
        unsigned long long hj = __shfl(h, j, 64);
        if (j != g && hj == h) {
            active = true;
            if (j < rep) rep = j;
            float wj = __shfl(wu, j, 64);
            atomicAdd(&K[(g << 6) | j], (double)wu * (double)wj);
        }
    }
    cls1[idx] = (unsigned char)rep;
    unsigned long long b = __ballot(active);
    if (b) {
        int lane = threadIdx.x & 63;
        int leader = (int)__ffsll(b) - 1;
        int bp = 0;
        if (lane == leader) bp = atomicAdd(nact, (int)__popcll(b));
        bp = __shfl(bp, leader, 64);
        if (active) {
            int p = bp + (int)__popcll(b & ((1ull << lane) - 1ull));
            if (p < GN) act[p] = idx;          // (u<<6)|g
        }
    }
}

// Refine active pairs: sig = (own class, multiset of (v, cls_{t-1}[v][g])).
// Tiny CAS region dedups within (u, prev-class); joiners add pairs + ovf.
__global__ __launch_bounds__(256) void
k_refine(const int* __restrict__ act, const int* __restrict__ nact,
         const int* __restrict__ nbr, const unsigned char* __restrict__ clsA,
         unsigned char* __restrict__ clsB, unsigned long long* __restrict__ table,
         const float* __restrict__ w, double* __restrict__ K,
         unsigned long long* __restrict__ ovf, int* __restrict__ novf,
         unsigned long long salt) {
    int n = *nact;
    if (n > GN) n = GN;
    for (int i = blockIdx.x * blockDim.x + threadIdx.x; i < n;
         i += gridDim.x * blockDim.x) {
        int p = act[i];
        int u = p >> 6, g = p & 63;
        unsigned own = clsA[p];
        const int4* nb4 = reinterpret_cast<const int4*>(nbr + ((size_t)((g << 12) | u)) * DD);
        unsigned long long acc = 0;
#pragma unroll
        for (int q = 0; q < 4; ++q) {
            int4 v = nb4[q];
            acc += mix64(((unsigned long long)(unsigned)v.x << 8) | clsA[(v.x << 6) | g])
                 + mix64(((unsigned long long)(unsigned)v.y << 8) | clsA[(v.y << 6) | g])
                 + mix64(((unsigned long long)(unsigned)v.z << 8) | clsA[(v.z << 6) | g])
                 + mix64(((unsigned long long)(unsigned)v.w << 8) | clsA[(v.w << 6) | g]);
        }
        unsigned long long h =
            mix64(acc ^ mix64((((unsigned long long)(unsigned)u << 8) | own) + salt));
        unsigned pos = (unsigned)h & RMASK;
        unsigned tag = (unsigned)(h >> 32);
        unsigned long long val = ((unsigned long long)tag << 32) | (unsigned)(p + 1);
        int repp = -1;
        while (true) {
            unsigned long long old = atomicCAS(&table[pos], 0ull, val);
            if (old == 0ull) break;
            if ((unsigned)(old >> 32) == tag) { repp = (int)(old & 0xFFFFFFFFull) - 1; break; }
            pos = (pos + 1) & RMASK;
        }
        if (repp < 0) {
            clsB[p] = (unsigned char)g;
        } else {
            int gr = repp & 63;
            clsB[p] = (unsigned char)gr;
            double duv = (double)w[(g << 12) | u] * (double)w[(gr << 12) | u];
            atomicAdd(&K[(g << 6) | gr], duv);
            atomicAdd(&K[(gr << 6) | g], duv);
            int q = atomicAdd(novf, 1);
            if (q < OVFR)
                ovf[q] = ((unsigned long long)pos << 32) | (unsigned)((g << 12) | u);
        }
    }
}

// Joiner-joiner ordered pairs (same slot => same class). Usually n == 0.
__global__ void k_resolve(const unsigned long long* __restrict__ ovf,
                          const int* __restrict__ novf,
                          const float* __restrict__ w, double* __restrict__ K) {
    int n = *novf;
    if (n > OVFR) n = OVFR;
    for (int i = blockIdx.x * blockDim.x + threadIdx.x; i < n;
         i += gridDim.x * blockDim.x) {
        unsigned long long e = ovf[i];
        unsigned pos = (unsigned)(e >> 32);
        int uidx = (int)(e & 0xFFFFFFFFull);
        int gu = uidx >> 12;
        double wu = w[uidx];
        for (int j = 0; j < n; ++j) {
            if (j == i) continue;
            unsigned long long f = ovf[j];
            if ((unsigned)(f >> 32) != pos) continue;
            int v = (int)(f & 0xFFFFFFFFull);
            atomicAdd(&K[(gu << 6) | (v >> 12)], wu * (double)w[v]);
        }
    }
}

// s_g = sum_u w[g][u]^2  (one block per graph)
__global__ void k_diag(const float* __restrict__ w, double* __restrict__ sdiag) {
    int g = blockIdx.x;
    const float4* w4 = reinterpret_cast<const float4*>(w + (g << 12));
    double s = 0.0;
    for (int k = threadIdx.x; k < NN / 4; k += 256) {
        float4 v = w4[k];
        s += (double)v.x * v.x + (double)v.y * v.y
           + (double)v.z * v.z + (double)v.w * v.w;
    }
#pragma unroll
    for (int o = 32; o > 0; o >>= 1) s += __shfl_down(s, o, 64);
    __shared__ double part[4];
    if ((threadIdx.x & 63) == 0) part[threadIdx.x >> 6] = s;
    __syncthreads();
    if (threadIdx.x == 0) sdiag[g] = part[0] + part[1] + part[2] + part[3];
}

// Fold K += src^T * src over [rows][64]; thread owns 4x4 tile of 64x64 K.
__global__ void k_fold(const float* __restrict__ src, double* __restrict__ K,
                       int chunk) {
    int e0 = blockIdx.x * chunk;
    __shared__ float v[32 * 64];
    float acc[16];
#pragma unroll
    for (int k = 0; k < 16; ++k) acc[k] = 0.f;
    int r0 = (threadIdx.x >> 4) << 2;
    int c0 = (threadIdx.x & 15) << 2;

    for (int s0 = 0; s0 < chunk; s0 += 32) {
        const float4* s4 = reinterpret_cast<const float4*>(src + (size_t)(e0 + s0) * 64);
        float4* dv = reinterpret_cast<float4*>(v);
        dv[threadIdx.x] = s4[threadIdx.x];
        dv[threadIdx.x + 256] = s4[threadIdx.x + 256];
        __syncthreads();
#pragma unroll
        for (int e = 0; e < 32; ++e) {
            const float4 a = *reinterpret_cast<const float4*>(&v[e * 64 + r0]);
            const float4 b = *reinterpret_cast<const float4*>(&v[e * 64 + c0]);
            acc[0]  += a.x * b.x; acc[1]  += a.x * b.y; acc[2]  += a.x * b.z; acc[3]  += a.x * b.w;
            acc[4]  += a.y * b.x; acc[5]  += a.y * b.y; acc[6]  += a.y * b.z; acc[7]  += a.y * b.w;
            acc[8]  += a.z * b.x; acc[9]  += a.z * b.y; acc[10] += a.z * b.z; acc[11] += a.z * b.w;
            acc[12] += a.w * b.x; acc[13] += a.w * b.y; acc[14] += a.w * b.z; acc[15] += a.w * b.w;
        }
        __syncthreads();
    }
#pragma unroll
    for (int i = 0; i < 4; ++i)
#pragma unroll
        for (int j = 0; j < 4; ++j)
            atomicAdd(&K[(r0 + i) * 64 + (c0 + j)], (double)acc[i * 4 + j]);
}

__global__ void k_norm(const double* __restrict__ K, const double* __restrict__ sdiag,
                       float* __restrict__ out) {
    int idx = blockIdx.x * blockDim.x + threadIdx.x;   // 4096
    int r = idx >> 6, c = idx & 63;
    double kd = K[idx] + (r == c ? 4.0 * sdiag[r] : 0.0);
    double dr = K[(r << 6) | r] + 4.0 * sdiag[r];
    double dc = K[(c << 6) | c] + 4.0 * sdiag[c];
    out[idx] = (float)(kd / sqrt(dr * dc));
}

extern "C" void kernel_launch(void* const* d_in, const int* in_sizes, int n_in,
                              void* d_out, int out_size, void* d_ws, size_t ws_size,
                              hipStream_t stream) {
    const int* nbr = (const int*)d_in[0];       // [G, N, D] int32
    const float* w = (const float*)d_in[1];     // [G, N] float32
    float* out = (float*)d_out;                 // [G, G] float32

    char* ws = (char*)d_ws;
    size_t off = 0;
    auto alloc = [&](size_t bytes) -> void* {
        void* p = ws + off;
        off += (bytes + 255) & ~(size_t)255;
        return p;
    };
    double* Kacc  = (double*)alloc(64 * 64 * 8);                    // 32 KB
    int* counters = (int*)alloc(256);                               // [0]=nact, [1..3]=novf
    double* sdiag = (double*)alloc(64 * 8);                         // 512 B
    unsigned long long* table = (unsigned long long*)alloc(3 * RTBYTES); // 12 MB
    unsigned long long* H = (unsigned long long*)alloc((size_t)GN * 8);  // 2 MB
    unsigned char* cls1 = (unsigned char*)alloc((size_t)GN);        // 256 KB
    unsigned char* cls2 = (unsigned char*)alloc((size_t)GN);        // 256 KB
    float* wT     = (float*)alloc((size_t)GN * 4);                  // 1 MB
    int* act      = (int*)alloc((size_t)GN * 4);                    // 1 MB
    unsigned long long* ovf = (unsigned long long*)alloc((size_t)3 * OVFR * 8); // 6 MB

    // Kacc, counters, sdiag, table contiguous -> ONE zero-memset per call
    hipMemsetAsync(Kacc, 0, 64 * 64 * 8 + 256 + 512 + 3 * RTBYTES, stream);

    const int BLK = 256;

    // t=0: labels = arange shared across graphs -> K0 = W W^T; cls2 = identity
    k_init<<<GN / BLK, BLK, 0, stream>>>(w, wT, cls2);
    k_fold<<<32, BLK, 0, stream>>>(wT, Kacc, NN / 32);
    k_diag<<<GG, BLK, 0, stream>>>(w, sdiag);

    // t=1: per-u wave-local dedup (no global atomics)
    k_sig<<<GN / BLK, BLK, 0, stream>>>(nbr, H);
    k_scan<<<GN / BLK, BLK, 0, stream>>>(H, w, Kacc, cls1, act, &counters[0]);

    // t=2..4: refine active pairs only (expected zero)
    unsigned char* A = cls1;
    unsigned char* B = cls2;
    for (int t = 0; t < 3; ++t) {
        unsigned long long salt = 0x13579BDF2468ACE1ull + ((unsigned long long)(t + 1) << 37);
        k_refine<<<128, BLK, 0, stream>>>(act, &counters[0], nbr, A, B,
                                          table + ((size_t)t << RBITS), w, Kacc,
                                          ovf + (size_t)t * OVFR, &counters[1 + t], salt);
        k_resolve<<<64, BLK, 0, stream>>>(ovf + (size_t)t * OVFR, &counters[1 + t], w, Kacc);
        unsigned char* tmp = A; A = B; B = tmp;
    }

    k_norm<<<(GG * GG) / BLK, BLK, 0, stream>>>(Kacc, sdiag, out);
}